// Round 4
// baseline (1066.556 us; speedup 1.0000x reference)
//
#include <hip/hip_runtime.h>
#include <cstddef>

#define T_LEN 512
#define IN_D 8
#define H 32
#define KP 40            // state row: 32 h + 8 x = 160 B, 16B-aligned
#define NBW 4            // batches per workgroup (one wave)
#define NT 64
#define LOG2E 1.44269504088896341f

__device__ __forceinline__ float fexp2(float v) {
#if __has_builtin(__builtin_amdgcn_exp2f)
    return __builtin_amdgcn_exp2f(v);
#else
    return exp2f(v);
#endif
}
__device__ __forceinline__ float frcp(float v) {
#if __has_builtin(__builtin_amdgcn_rcpf)
    return __builtin_amdgcn_rcpf(v);
#else
    return 1.0f / v;
#endif
}

// lane = gp*32 + j.  j = hidden unit, gp selects gate pair:
//   gp=0 -> rows (i: j), (f: 32+j)      gp=1 -> rows (g: 64+j), (o: 96+j)
// Each thread: 2 gate-rows x 40 k = 80 W floats = 20 float4 -> REGISTER-RESIDENT
// (round-3 failure: 160 floats/thread was demoted to scratch; VGPR_Count=108).
// All threads process all 4 WG batches; gate recombine via __shfl_xor(.,32).
// Activation divergence avoided: act(v) = a0 + b0*rcp(1+exp2(k0*v)) with per-lane
// constants (gp=0: sigmoid of i; gp=1: tanh of g) -> single uniform instruction path.
// gp=1 lanes' c is garbage but bounded (exp2 overflow -> inf -> rcp=0 -> tanh=1; no NaN).
__global__ void __launch_bounds__(NT, 2) lstm_fused(
    const float* __restrict__ x, const float* __restrict__ W_ih,
    const float* __restrict__ W_hh, const float* __restrict__ b_ih,
    const float* __restrict__ b_hh, const float* __restrict__ W_fc,
    const float* __restrict__ b_fc, float* __restrict__ out)
{
    __shared__ __align__(16) float st[2][NBW][KP];

    const int tid = threadIdx.x;
    const int j   = tid & 31;
    const int gp  = tid >> 5;
    const int r0  = gp * 64 + j;        // i-row or g-row
    const int r1  = r0 + 32;            // f-row or o-row

    // ---- W into 20 float4 registers ----
    float4 wA[10], wB[10];
    #pragma unroll
    for (int q = 0; q < 8; ++q) {
        wA[q] = *(const float4*)(W_hh + (size_t)r0 * H + q * 4);
        wB[q] = *(const float4*)(W_hh + (size_t)r1 * H + q * 4);
    }
    #pragma unroll
    for (int q = 0; q < 2; ++q) {
        wA[8 + q] = *(const float4*)(W_ih + (size_t)r0 * IN_D + q * 4);
        wB[8 + q] = *(const float4*)(W_ih + (size_t)r1 * IN_D + q * 4);
    }
    const float bias0 = b_ih[r0] + b_hh[r0];
    const float bias1 = b_ih[r1] + b_hh[r1];

    // slot-0 activation params: gp=0 sigmoid, gp=1 tanh
    const float k0 = gp ? 2.0f * LOG2E : -LOG2E;
    const float a0 = gp ? 1.0f : 0.0f;
    const float b0 = gp ? -2.0f : 1.0f;

    const int xb = j >> 3, xd = j & 7;  // 32 lanes cover 4 batches x 8 dims
    const float* xp = x + (size_t)(blockIdx.x * NBW + xb) * (size_t)(T_LEN * IN_D) + xd;

    // init: h0 = 0, x[0] staged
    for (int i = tid; i < NBW * H; i += NT) st[0][i >> 5][i & 31] = 0.0f;
    if (gp) st[0][xb][H + xd] = xp[0];
    float c[NBW];
    #pragma unroll
    for (int b = 0; b < NBW; ++b) c[b] = 0.0f;
    float xnext = xp[IN_D];
    __syncthreads();

    auto step = [&](const float (*scur)[KP], float (*snxt)[KP], float xn) {
        float acc0[NBW], acc1[NBW];
        #pragma unroll
        for (int b = 0; b < NBW; ++b) { acc0[b] = bias0; acc1[b] = bias1; }

        #pragma unroll
        for (int kb = 0; kb < 10; ++kb) {
            const float4 w0 = wA[kb], w1 = wB[kb];
            #pragma unroll
            for (int b = 0; b < NBW; ++b) {
                const float4 sv = *(const float4*)(&scur[b][kb * 4]);  // wave-broadcast
                acc0[b] += w0.x * sv.x + w0.y * sv.y + w0.z * sv.z + w0.w * sv.w;
                acc1[b] += w1.x * sv.x + w1.y * sv.y + w1.z * sv.z + w1.w * sv.w;
            }
        }

        float t0[NBW], t1[NBW], q0[NBW], q1[NBW], h[NBW];
        #pragma unroll
        for (int b = 0; b < NBW; ++b)
            t0[b] = a0 + b0 * frcp(1.0f + fexp2(k0 * acc0[b]));        // sigm(i) | tanh(g)
        #pragma unroll
        for (int b = 0; b < NBW; ++b)
            t1[b] = frcp(1.0f + fexp2(-LOG2E * acc1[b]));              // sigm(f) | sigm(o)
        #pragma unroll
        for (int b = 0; b < NBW; ++b) {
            q0[b] = __shfl_xor(t0[b], 32);                             // gp0 gets tanh(g)
            q1[b] = __shfl_xor(t1[b], 32);                             // gp0 gets sigm(o)
        }
        #pragma unroll
        for (int b = 0; b < NBW; ++b) {
            c[b] = t1[b] * c[b] + t0[b] * q0[b];                       // gp0: real c
            const float tc = 1.0f - 2.0f * frcp(1.0f + fexp2(2.0f * LOG2E * c[b]));
            h[b] = q1[b] * tc;                                         // gp0: real h
        }
        if (!gp) {
            #pragma unroll
            for (int b = 0; b < NBW; ++b) snxt[b][j] = h[b];           // conflict-free
        } else {
            snxt[xb][H + xd] = xn;                                     // conflict-free (KP=40)
        }
        __syncthreads();   // single-wave WG: compiles to a cheap waitcnt+barrier
    };

    for (int t = 0; t < T_LEN; t += 2) {
        const int ia = (t + 2 < T_LEN) ? t + 2 : T_LEN - 1;
        const int ib = (t + 3 < T_LEN) ? t + 3 : T_LEN - 1;
        const float xa = xp[(size_t)ia * IN_D];   // depth-2 prefetch
        const float xc = xp[(size_t)ib * IN_D];
        step(st[0], st[1], xnext);
        step(st[1], st[0], xa);
        xnext = xc;
    }

    // epilogue: out[b] = h_n . W_fc + b_fc   (h_n in st[0] after even step count)
    if (tid < NBW) {
        float s = b_fc[0];
        #pragma unroll
        for (int jj = 0; jj < H; ++jj) s += st[0][tid][jj] * W_fc[jj];
        out[blockIdx.x * NBW + tid] = s;
    }
}

extern "C" void kernel_launch(void* const* d_in, const int* in_sizes, int n_in,
                              void* d_out, int out_size, void* d_ws, size_t ws_size,
                              hipStream_t stream) {
    const float* x    = (const float*)d_in[0];
    const float* W_ih = (const float*)d_in[1];
    const float* W_hh = (const float*)d_in[2];
    const float* b_ih = (const float*)d_in[3];
    const float* b_hh = (const float*)d_in[4];
    const float* W_fc = (const float*)d_in[5];
    const float* b_fc = (const float*)d_in[6];
    float* out = (float*)d_out;
    const int Bn = in_sizes[0] / (T_LEN * IN_D);   // 8192
    lstm_fused<<<dim3(Bn / NBW), dim3(NT), 0, stream>>>(
        x, W_ih, W_hh, b_ih, b_hh, W_fc, b_fc, out);
}

// Round 5
// 887.968 us; speedup vs baseline: 1.2011x; 1.2011x over previous
//
#include <hip/hip_runtime.h>
#include <cstddef>

#define T_LEN 512
#define IN_D 8
#define H 32
#define KP 40            // state row: 32 h + 8 x = 160 B, 16B-aligned
#define NBW 2            // batches per workgroup (one wave) -> grid 4096 = 4 waves/SIMD
#define NT 64
#define LOG2E 1.44269504088896341f

__device__ __forceinline__ float fexp2(float v) {
#if __has_builtin(__builtin_amdgcn_exp2f)
    return __builtin_amdgcn_exp2f(v);
#else
    return exp2f(v);
#endif
}
__device__ __forceinline__ float frcp(float v) {
#if __has_builtin(__builtin_amdgcn_rcpf)
    return __builtin_amdgcn_rcpf(v);
#else
    return 1.0f / v;
#endif
}

// lane = gp*32 + j.  j = hidden unit, gp selects gate pair:
//   gp=0 -> rows (i: j), (f: 32+j)      gp=1 -> rows (g: 64+j), (o: 96+j)
// Thread: 2 gate-rows x 40 k in 80 VGPRs (register-resident, validated r4),
// for both WG batches. Gate recombine via __shfl_xor(.,32).
// KEY r5 changes:
//  - NO __syncthreads in the step loop. WG = single wave; LDS ops from one wave
//    are processed in order, so cross-lane LDS visibility needs no barrier.
//    This removes the per-step s_waitcnt vmcnt(0) drain that was killing the
//    x-prefetch pipeline (r4: ~3000 stall cyc/step).
//  - NBW=2 -> 4096 WGs = 4 waves/SIMD for latency hiding (was 2).
__global__ void __launch_bounds__(NT, 4) lstm_fused(
    const float* __restrict__ x, const float* __restrict__ W_ih,
    const float* __restrict__ W_hh, const float* __restrict__ b_ih,
    const float* __restrict__ b_hh, const float* __restrict__ W_fc,
    const float* __restrict__ b_fc, float* __restrict__ out)
{
    __shared__ __align__(16) float st[2][NBW][KP];

    const int tid = threadIdx.x;
    const int j   = tid & 31;
    const int gp  = tid >> 5;
    const int r0  = gp * 64 + j;        // i-row or g-row
    const int r1  = r0 + 32;            // f-row or o-row

    // ---- W into 20 float4 registers ----
    float4 wA[10], wB[10];
    #pragma unroll
    for (int q = 0; q < 8; ++q) {
        wA[q] = *(const float4*)(W_hh + (size_t)r0 * H + q * 4);
        wB[q] = *(const float4*)(W_hh + (size_t)r1 * H + q * 4);
    }
    #pragma unroll
    for (int q = 0; q < 2; ++q) {
        wA[8 + q] = *(const float4*)(W_ih + (size_t)r0 * IN_D + q * 4);
        wB[8 + q] = *(const float4*)(W_ih + (size_t)r1 * IN_D + q * 4);
    }
    const float bias0 = b_ih[r0] + b_hh[r0];
    const float bias1 = b_ih[r1] + b_hh[r1];

    // slot-0 activation params: gp=0 sigmoid(i), gp=1 tanh(g) — uniform instr path
    const float k0 = gp ? 2.0f * LOG2E : -LOG2E;
    const float a0 = gp ? 1.0f : 0.0f;
    const float b0 = gp ? -2.0f : 1.0f;

    // x staging: 16 lanes (of gp=1) cover 2 batches x 8 dims
    const int xb = (j >> 3) & 1, xd = j & 7;
    const bool xw = (gp == 1) && (j < 16);
    const float* xp = x + (size_t)(blockIdx.x * NBW + xb) * (size_t)(T_LEN * IN_D) + xd;

    // init: h0 = 0, x[0] staged (single wave: no barrier needed, LDS in-order)
    if (tid < NBW * H) st[0][tid >> 5][tid & 31] = 0.0f;
    if (xw) st[0][xb][H + xd] = xp[0];
    float c[NBW];
    #pragma unroll
    for (int b = 0; b < NBW; ++b) c[b] = 0.0f;
    float xnext = xp[IN_D];

    auto step = [&](const float (*scur)[KP], float (*snxt)[KP], float xn) {
        float acc0[NBW], acc1[NBW];
        #pragma unroll
        for (int b = 0; b < NBW; ++b) { acc0[b] = bias0; acc1[b] = bias1; }

        #pragma unroll
        for (int kb = 0; kb < 10; ++kb) {
            const float4 w0 = wA[kb], w1 = wB[kb];
            #pragma unroll
            for (int b = 0; b < NBW; ++b) {
                const float4 sv = *(const float4*)(&scur[b][kb * 4]);  // wave-broadcast
                acc0[b] += w0.x * sv.x + w0.y * sv.y + w0.z * sv.z + w0.w * sv.w;
                acc1[b] += w1.x * sv.x + w1.y * sv.y + w1.z * sv.z + w1.w * sv.w;
            }
        }

        float t0[NBW], t1[NBW], q0[NBW], q1[NBW];
        #pragma unroll
        for (int b = 0; b < NBW; ++b)
            t0[b] = a0 + b0 * frcp(1.0f + fexp2(k0 * acc0[b]));        // sigm(i) | tanh(g)
        #pragma unroll
        for (int b = 0; b < NBW; ++b)
            t1[b] = frcp(1.0f + fexp2(-LOG2E * acc1[b]));              // sigm(f) | sigm(o)
        #pragma unroll
        for (int b = 0; b < NBW; ++b) {
            q0[b] = __shfl_xor(t0[b], 32);                             // gp0 gets tanh(g)
            q1[b] = __shfl_xor(t1[b], 32);                             // gp0 gets sigm(o)
        }
        #pragma unroll
        for (int b = 0; b < NBW; ++b) {
            c[b] = t1[b] * c[b] + t0[b] * q0[b];                       // gp0: real c
            // gp1 lanes: c garbage but bounded (exp2->inf->rcp->0->tanh=1; no NaN)
            const float tc = 1.0f - 2.0f * frcp(1.0f + fexp2(2.0f * LOG2E * c[b]));
            if (!gp) snxt[b][j] = q1[b] * tc;                          // h, conflict-free
        }
        if (xw) snxt[xb][H + xd] = xn;
        // no barrier: single-wave WG, per-wave LDS ordering guarantees visibility
    };

    for (int t = 0; t < T_LEN; t += 2) {
        const int ia = (t + 2 < T_LEN) ? t + 2 : T_LEN - 1;
        const int ib = (t + 3 < T_LEN) ? t + 3 : T_LEN - 1;
        const float xa = xp[(size_t)ia * IN_D];   // prefetch floats free: no vmcnt drain
        const float xc = xp[(size_t)ib * IN_D];
        step(st[0], st[1], xnext);
        step(st[1], st[0], xa);
        xnext = xc;
    }

    // epilogue: out[b] = h_n . W_fc + b_fc   (h_n in st[0]; same-wave, no barrier)
    if (tid < NBW) {
        float s = b_fc[0];
        #pragma unroll
        for (int jj = 0; jj < H; ++jj) s += st[0][tid][jj] * W_fc[jj];
        out[blockIdx.x * NBW + tid] = s;
    }
}

extern "C" void kernel_launch(void* const* d_in, const int* in_sizes, int n_in,
                              void* d_out, int out_size, void* d_ws, size_t ws_size,
                              hipStream_t stream) {
    const float* x    = (const float*)d_in[0];
    const float* W_ih = (const float*)d_in[1];
    const float* W_hh = (const float*)d_in[2];
    const float* b_ih = (const float*)d_in[3];
    const float* b_hh = (const float*)d_in[4];
    const float* W_fc = (const float*)d_in[5];
    const float* b_fc = (const float*)d_in[6];
    float* out = (float*)d_out;
    const int Bn = in_sizes[0] / (T_LEN * IN_D);   // 8192
    lstm_fused<<<dim3(Bn / NBW), dim3(NT), 0, stream>>>(
        x, W_ih, W_hh, b_ih, b_hh, W_fc, b_fc, out);
}

// Round 6
// 694.893 us; speedup vs baseline: 1.5348x; 1.2778x over previous
//
#include <hip/hip_runtime.h>
#include <cstddef>

#define T_LEN 512
#define IN_D 8
#define H 32
#define NBATCH 16        // batches per wave = MFMA M
#define NT 64
#define LOG2E 1.44269504088896341f

typedef __attribute__((ext_vector_type(8))) short bf16x8;
typedef __attribute__((ext_vector_type(4))) float f32x4;

__device__ __forceinline__ float fexp2(float v) {
#if __has_builtin(__builtin_amdgcn_exp2f)
    return __builtin_amdgcn_exp2f(v);
#else
    return exp2f(v);
#endif
}
__device__ __forceinline__ float frcp(float v) {
#if __has_builtin(__builtin_amdgcn_rcpf)
    return __builtin_amdgcn_rcpf(v);
#else
    return 1.0f / v;
#endif
}
__device__ __forceinline__ float sigm(float v)  { return frcp(1.f + fexp2(v * -LOG2E)); }
__device__ __forceinline__ float tanh_f(float v){ return 1.f - 2.f * frcp(1.f + fexp2(v * (2.f * LOG2E))); }

__device__ __forceinline__ unsigned short f2bf(float f) {   // RNE fp32->bf16
    unsigned u = __builtin_bit_cast(unsigned, f);
    u += 0x7FFF + ((u >> 16) & 1);
    return (unsigned short)(u >> 16);
}
__device__ __forceinline__ float bf2f(unsigned short b) {
    unsigned u = ((unsigned)b) << 16;
    return __builtin_bit_cast(float, u);
}

// One wave = 16 batches x 128 gate-rows via 8 MFMA N-tiles (16x16x32 bf16).
// Precision: W = Whi+Wlo, s = shi+slo (bf16 pairs); 3 terms Whi*shi + Whi*slo +
// Wlo*shi accumulated in fp32 C (bias preloaded into C). Dropped Wlo*slo ~2^-18.
// K-order permutation pi(j) = 2*(j&15) + (j>>4) applied to BOTH A (LDS h layout)
// and B (setup) so each lane's two units (c, c+16) pack into one ds_write_b32 and
// A-frags are single ds_read_b128. Tiles: T = 2*gate + (unit>=16); C/D layout
// (m89-verified): col = lane&15, row = (lane>>4)*4 + reg -> all 4 gates of unit
// (c | c+16) land in the SAME lane: gate-combine needs no cross-lane ops.
// Single wave per WG: no barriers (per-wave in-order LDS, validated r5).
__global__ void __launch_bounds__(NT, 1) lstm_mfma(
    const float* __restrict__ x, const float* __restrict__ W_ih,
    const float* __restrict__ W_hh, const float* __restrict__ b_ih,
    const float* __restrict__ b_hh, const float* __restrict__ W_fc,
    const float* __restrict__ b_fc, float* __restrict__ out)
{
    // h rows padded to 40 ushorts (80 B = 5x16) -> 16B-aligned b128 reads, write
    // conflicts only 2-way (free).
    __shared__ __align__(16) unsigned short hhi[NBATCH][40];
    __shared__ __align__(16) unsigned short hlo[NBATCH][40];
    __shared__ __align__(16) unsigned short xhi[NBATCH][8];
    __shared__ __align__(16) unsigned short xlo[NBATCH][8];
    __shared__ __align__(16) unsigned short zblk[8];

    const int lane = threadIdx.x;
    const int q = lane >> 4;          // k-quad (A/B), row-group (C/D)
    const int c = lane & 15;          // A row (batch) / B col (gate-row in tile)

    // ---- static B fragments: 4 kinds x 8 tiles, bf16 hi/lo ----
    bf16x8 Bh0[8], Bl0[8], Bh1[8], Bl1[8];
    float biasT[8];
    #pragma unroll
    for (int T = 0; T < 8; ++T) {
        const int r = 16 * T + c;                     // global gate-row
        #pragma unroll
        for (int j = 0; j < 8; ++j) {
            const int p = 8 * q + j;                  // k position (pi-order)
            const int u = 16 * (p & 1) + (p >> 1);    // unit index
            const float w = W_hh[r * H + u];
            const unsigned short whi = f2bf(w);
            Bh0[T][j] = (short)whi;
            Bl0[T][j] = (short)f2bf(w - bf2f(whi));
            const float wx = (q == 0) ? W_ih[r * IN_D + j] : 0.f;
            const unsigned short xwhi = f2bf(wx);
            Bh1[T][j] = (short)xwhi;
            Bl1[T][j] = (short)f2bf(wx - bf2f(xwhi));
        }
        biasT[T] = b_ih[r] + b_hh[r];
    }

    // ---- LDS init: h0 = 0, zero block ----
    {
        unsigned* ph = (unsigned*)&hhi[0][0];
        unsigned* pl = (unsigned*)&hlo[0][0];
        for (int i = lane; i < NBATCH * 40 / 2; i += NT) { ph[i] = 0u; pl[i] = 0u; }
        if (lane < 4) ((unsigned*)zblk)[lane] = 0u;
    }

    // ---- x staging: lane -> batch bx = lane>>2, dims 2*(lane&3), 2*(lane&3)+1 ----
    const int bx = lane >> 2, dd = lane & 3;
    const float* xp = x + (size_t)(blockIdx.x * NBATCH + bx) * (size_t)(T_LEN * IN_D) + 2 * dd;
    auto stage_x = [&](float2 xv) {
        const unsigned short h0 = f2bf(xv.x), h1 = f2bf(xv.y);
        const unsigned short l0 = f2bf(xv.x - bf2f(h0)), l1 = f2bf(xv.y - bf2f(h1));
        *(unsigned*)&xhi[bx][2 * dd] = ((unsigned)h1 << 16) | h0;
        *(unsigned*)&xlo[bx][2 * dd] = ((unsigned)l1 << 16) | l0;
    };
    stage_x(*(const float2*)xp);                       // x[0]
    float2 xnext = *(const float2*)(xp + IN_D);        // x[1]

    float cst[4][2];
    #pragma unroll
    for (int rg = 0; rg < 4; ++rg) { cst[rg][0] = 0.f; cst[rg][1] = 0.f; }

    for (int t = 0; t < T_LEN; ++t) {
        const int tp = (t + 2 < T_LEN) ? t + 2 : T_LEN - 1;
        const float2 xpref = *(const float2*)(xp + (size_t)tp * IN_D);

        // ---- A fragments (single b128 each; pi-order matches B) ----
        const bf16x8 A0 = *(const bf16x8*)&hhi[c][8 * q];                          // s_hi (h)
        const bf16x8 A2 = *(const bf16x8*)&hlo[c][8 * q];                          // s_lo (h)
        const bf16x8 A1 = *(const bf16x8*)((q == 0) ? &xhi[c][0] : &zblk[0]);      // x_hi
        const bf16x8 A3 = *(const bf16x8*)((q == 0) ? &xlo[c][0] : &zblk[0]);      // x_lo

        f32x4 C[8];
        #pragma unroll
        for (int T = 0; T < 8; ++T) {
            f32x4 acc = { biasT[T], biasT[T], biasT[T], biasT[T] };
            acc = __builtin_amdgcn_mfma_f32_16x16x32_bf16(A0, Bh0[T], acc, 0, 0, 0);
            acc = __builtin_amdgcn_mfma_f32_16x16x32_bf16(A1, Bh1[T], acc, 0, 0, 0);
            acc = __builtin_amdgcn_mfma_f32_16x16x32_bf16(A2, Bh0[T], acc, 0, 0, 0);
            acc = __builtin_amdgcn_mfma_f32_16x16x32_bf16(A3, Bh1[T], acc, 0, 0, 0);
            acc = __builtin_amdgcn_mfma_f32_16x16x32_bf16(A0, Bl0[T], acc, 0, 0, 0);
            acc = __builtin_amdgcn_mfma_f32_16x16x32_bf16(A1, Bl1[T], acc, 0, 0, 0);
            C[T] = acc;
        }

        // ---- activations: lane owns units {c, c+16}, batches m = 4q+reg ----
        float hv[4][2];
        #pragma unroll
        for (int rg = 0; rg < 4; ++rg) {
            #pragma unroll
            for (int jj = 0; jj < 2; ++jj) {
                const float ig = sigm(C[0 + jj][rg]);
                const float fg = sigm(C[2 + jj][rg]);
                const float gt = tanh_f(C[4 + jj][rg]);
                const float og = sigm(C[6 + jj][rg]);
                const float cc = fg * cst[rg][jj] + ig * gt;
                cst[rg][jj] = cc;
                hv[rg][jj] = og * tanh_f(cc);
            }
        }

        // ---- h -> LDS (bf16 hi/lo, pi-order: units (c, c+16) -> pos 2c, 2c+1) ----
        #pragma unroll
        for (int rg = 0; rg < 4; ++rg) {
            const int m = 4 * q + rg;
            const unsigned short h0 = f2bf(hv[rg][0]);
            const unsigned short h1 = f2bf(hv[rg][1]);
            const unsigned short l0 = f2bf(hv[rg][0] - bf2f(h0));
            const unsigned short l1 = f2bf(hv[rg][1] - bf2f(h1));
            *(unsigned*)&hhi[m][2 * c] = ((unsigned)h1 << 16) | h0;
            *(unsigned*)&hlo[m][2 * c] = ((unsigned)l1 << 16) | l0;
        }
        stage_x(xnext);            // x[t+1] visible before next iter's A1/A3 reads
        xnext = xpref;
    }

    // ---- epilogue: out[m] = h_n . W_fc + b_fc ----
    if (lane < NBATCH) {
        float s = b_fc[0];
        #pragma unroll
        for (int p = 0; p < 2 * H / 2; ++p) { }        // (no-op; keep loop below simple)
        for (int p = 0; p < H; ++p) {
            const int u = 16 * (p & 1) + (p >> 1);
            const float hvv = bf2f(hhi[lane][p]) + bf2f(hlo[lane][p]);
            s += hvv * W_fc[u];
        }
        out[blockIdx.x * NBATCH + lane] = s;
    }
}

extern "C" void kernel_launch(void* const* d_in, const int* in_sizes, int n_in,
                              void* d_out, int out_size, void* d_ws, size_t ws_size,
                              hipStream_t stream) {
    const float* x    = (const float*)d_in[0];
    const float* W_ih = (const float*)d_in[1];
    const float* W_hh = (const float*)d_in[2];
    const float* b_ih = (const float*)d_in[3];
    const float* b_hh = (const float*)d_in[4];
    const float* W_fc = (const float*)d_in[5];
    const float* b_fc = (const float*)d_in[6];
    float* out = (float*)d_out;
    const int Bn = in_sizes[0] / (T_LEN * IN_D);   // 8192
    lstm_mfma<<<dim3(Bn / NBATCH), dim3(NT), 0, stream>>>(
        x, W_ih, W_hh, b_ih, b_hh, W_fc, b_fc, out);
}

// Round 7
// 526.329 us; speedup vs baseline: 2.0264x; 1.3203x over previous
//
#include <hip/hip_runtime.h>
#include <cstddef>

#define T_LEN 512
#define IN_D 8
#define H 32
#define NBATCH 16        // batches per WG (MFMA M)
#define NT 256           // 4 waves: wave w owns gate w (0=i,1=f,2=g,3=o)
#define LOG2E 1.44269504088896341f

typedef __attribute__((ext_vector_type(8))) short bf16x8;
typedef __attribute__((ext_vector_type(4))) float f32x4;

__device__ __forceinline__ float fexp2(float v) { return __builtin_amdgcn_exp2f(v); }
__device__ __forceinline__ float frcp(float v)  { return __builtin_amdgcn_rcpf(v); }
__device__ __forceinline__ unsigned short f2bf(float f) {   // RNE fp32->bf16
    unsigned u = __builtin_bit_cast(unsigned, f);
    u += 0x7FFF + ((u >> 16) & 1);
    return (unsigned short)(u >> 16);
}
__device__ __forceinline__ float bf2f(unsigned short b) {
    unsigned u = ((unsigned)b) << 16;
    return __builtin_bit_cast(float, u);
}

// LDS-only barrier: no vmcnt drain (global x-chunk loads stay in flight across
// steps — the r4 lesson). "memory" clobber pins LDS ops on each side.
#define WG_BARRIER() asm volatile("s_waitcnt lgkmcnt(0)\n\ts_barrier" ::: "memory")

// 4 waves per WG, one gate per wave. Wave w: tiles T=2w,2w+1 (units 0-15,16-31),
// 12 MFMAs/step (2 accum chains of 3 per tile), uniform activation per wave.
// Gate exchange: G[4][16][40] fp32 (pad 40 -> bank 8m+u, <=2-way = free).
// c/h update: thread tix -> batch m=tix>>4, units u0=tix&15, u0+16 (2 pairs).
// h stored bf16 hi/lo in pi-order (pi(u)=2(u&15)+(u>>4)): units (u0,u0+16) pack
// into ONE b32 write; A-frags load as single b128 (layouts verified in r6,
// absmax 9.8e-4). x chunk-loaded 8 steps/float4/thread, converted once per chunk.
__global__ void __launch_bounds__(NT, 2) lstm_mfma4(
    const float* __restrict__ x, const float* __restrict__ W_ih,
    const float* __restrict__ W_hh, const float* __restrict__ b_ih,
    const float* __restrict__ b_hh, const float* __restrict__ W_fc,
    const float* __restrict__ b_fc, float* __restrict__ out)
{
    __shared__ __align__(16) unsigned short hhi[NBATCH][40];   // h hi, pi-order, pad 40
    __shared__ __align__(16) unsigned short hlo[NBATCH][40];
    __shared__ __align__(16) unsigned short xh[8][NBATCH][8];  // x chunk (8 steps) hi
    __shared__ __align__(16) unsigned short xl[8][NBATCH][8];
    __shared__ __align__(16) float G[4][NBATCH][40];           // activated gates
    __shared__ __align__(16) unsigned short zblk[8];

    const int tix  = threadIdx.x;
    const int w    = tix >> 6;          // gate id
    const int lane = tix & 63;
    const int q    = lane >> 4;         // k-quad (A/B) / row-group (C)
    const int cc   = lane & 15;         // A row (batch) / B col (unit-in-tile)

    // ---- static B fragments for gate w only: 2 tiles x {Whh hi/lo, Wih hi/lo} ----
    bf16x8 Bh[2], Bl[2], Bxh[2], Bxl[2];
    float bias[2];
    #pragma unroll
    for (int d = 0; d < 2; ++d) {
        const int r = 16 * (2 * w + d) + cc;          // global gate-row
        #pragma unroll
        for (int j = 0; j < 8; ++j) {
            const int p = 8 * q + j;                  // k position (pi-order)
            const int u = 16 * (p & 1) + (p >> 1);    // unit index
            const float wv = W_hh[r * H + u];
            const unsigned short whi = f2bf(wv);
            Bh[d][j] = (short)whi;
            Bl[d][j] = (short)f2bf(wv - bf2f(whi));
            const float wx = (q == 0) ? W_ih[r * IN_D + j] : 0.f;
            const unsigned short xwhi = f2bf(wx);
            Bxh[d][j] = (short)xwhi;
            Bxl[d][j] = (short)f2bf(wx - bf2f(xwhi));
        }
        bias[d] = b_ih[r] + b_hh[r];
    }

    // activation params (uniform per wave): g-gate -> tanh, else sigmoid
    const float kk = (w == 2) ? 2.f * LOG2E : -LOG2E;
    const float aa = (w == 2) ? 1.f : 0.f;
    const float bb = (w == 2) ? -2.f : 1.f;

    // ---- x chunk machinery: thread -> (batch xb, step-in-chunk xs, half xhf) ----
    const int xb = tix >> 4, xs = (tix >> 1) & 7, xhf = tix & 1;
    const float* xbase = x + (size_t)(blockIdx.x * NBATCH + xb) * (size_t)(T_LEN * IN_D)
                           + xs * IN_D + 4 * xhf;
    auto ldchunk = [&](int ch) { return *(const float4*)(xbase + (size_t)ch * 8 * IN_D); };
    auto cvchunk = [&](float4 v) {
        const float vv[4] = { v.x, v.y, v.z, v.w };
        unsigned short h4[4], l4[4];
        #pragma unroll
        for (int k = 0; k < 4; ++k) {
            h4[k] = f2bf(vv[k]);
            l4[k] = f2bf(vv[k] - bf2f(h4[k]));
        }
        *(unsigned*)&xh[xs][xb][4 * xhf]     = ((unsigned)h4[1] << 16) | h4[0];
        *(unsigned*)&xh[xs][xb][4 * xhf + 2] = ((unsigned)h4[3] << 16) | h4[2];
        *(unsigned*)&xl[xs][xb][4 * xhf]     = ((unsigned)l4[1] << 16) | l4[0];
        *(unsigned*)&xl[xs][xb][4 * xhf + 2] = ((unsigned)l4[3] << 16) | l4[2];
    };

    // ---- init: h0 = 0, zblk = 0, x chunk 0 staged, chunk 1 in flight ----
    for (int i = tix; i < NBATCH * 40 / 2; i += NT) {
        ((unsigned*)hhi)[i] = 0u;
        ((unsigned*)hlo)[i] = 0u;
    }
    if (tix < 4) ((unsigned*)zblk)[tix] = 0u;
    cvchunk(ldchunk(0));
    float4 xbuf = ldchunk(1);
    __syncthreads();    // once; full drain acceptable outside the loop

    // c-update ownership: batch m, units u0 / u0+16
    const int m = tix >> 4, u0 = tix & 15;
    float cs0 = 0.f, cs1 = 0.f;

    for (int t = 0; t < T_LEN; ++t) {
        // ---- A fragments (shared by all 4 waves; b128 each) ----
        const bf16x8 A0 = *(const bf16x8*)&hhi[cc][8 * q];
        const bf16x8 A2 = *(const bf16x8*)&hlo[cc][8 * q];
        const unsigned short* sH = (q == 0) ? &xh[t & 7][cc][0] : zblk;
        const unsigned short* sL = (q == 0) ? &xl[t & 7][cc][0] : zblk;
        const bf16x8 A1 = *(const bf16x8*)sH;
        const bf16x8 A3 = *(const bf16x8*)sL;

        // ---- 12 MFMAs: per tile, 2 chains of 3 (halve dependent latency) ----
        f32x4 C[2];
        #pragma unroll
        for (int d = 0; d < 2; ++d) {
            f32x4 a1 = { bias[d], bias[d], bias[d], bias[d] };
            f32x4 a2 = { 0.f, 0.f, 0.f, 0.f };
            a1 = __builtin_amdgcn_mfma_f32_16x16x32_bf16(A0, Bh[d],  a1, 0, 0, 0);
            a2 = __builtin_amdgcn_mfma_f32_16x16x32_bf16(A1, Bxh[d], a2, 0, 0, 0);
            a1 = __builtin_amdgcn_mfma_f32_16x16x32_bf16(A2, Bh[d],  a1, 0, 0, 0);
            a2 = __builtin_amdgcn_mfma_f32_16x16x32_bf16(A3, Bxh[d], a2, 0, 0, 0);
            a1 = __builtin_amdgcn_mfma_f32_16x16x32_bf16(A0, Bl[d],  a1, 0, 0, 0);
            a2 = __builtin_amdgcn_mfma_f32_16x16x32_bf16(A1, Bxl[d], a2, 0, 0, 0);
            C[d] = a1 + a2;
        }

        // ---- uniform activation, write to exchange array ----
        #pragma unroll
        for (int d = 0; d < 2; ++d)
            #pragma unroll
            for (int rg = 0; rg < 4; ++rg)
                G[w][4 * q + rg][cc + 16 * d] = aa + bb * frcp(1.f + fexp2(kk * C[d][rg]));

        WG_BARRIER();

        // ---- c/h update: 2 unit-batch pairs per thread ----
        {
            const float i0 = G[0][m][u0], i1 = G[0][m][u0 + 16];
            const float f0 = G[1][m][u0], f1 = G[1][m][u0 + 16];
            const float g0 = G[2][m][u0], g1 = G[2][m][u0 + 16];
            const float o0 = G[3][m][u0], o1 = G[3][m][u0 + 16];
            cs0 = f0 * cs0 + i0 * g0;
            cs1 = f1 * cs1 + i1 * g1;
            const float t0 = 1.f - 2.f * frcp(1.f + fexp2(2.f * LOG2E * cs0));
            const float t1 = 1.f - 2.f * frcp(1.f + fexp2(2.f * LOG2E * cs1));
            const float h0 = o0 * t0, h1 = o1 * t1;
            const unsigned short a_ = f2bf(h0), b_ = f2bf(h1);
            *(unsigned*)&hhi[m][2 * u0] = ((unsigned)b_ << 16) | a_;    // pi: 2u0, 2u0+1
            const unsigned short la = f2bf(h0 - bf2f(a_)), lb = f2bf(h1 - bf2f(b_));
            *(unsigned*)&hlo[m][2 * u0] = ((unsigned)lb << 16) | la;
        }

        // ---- chunk boundary: stage next 8 steps of x, refill pipeline ----
        if ((t & 7) == 7) {
            cvchunk(xbuf);
            int nc = (t >> 3) + 2;
            if (nc > (T_LEN / 8) - 1) nc = (T_LEN / 8) - 1;
            xbuf = ldchunk(nc);
        }

        WG_BARRIER();
    }

    // ---- epilogue: out[m] = h_n . W_fc + b_fc ----
    if (tix < NBATCH) {
        float s = b_fc[0];
        #pragma unroll
        for (int p = 0; p < H; ++p) {
            const int u = 16 * (p & 1) + (p >> 1);
            s += (bf2f(hhi[tix][p]) + bf2f(hlo[tix][p])) * W_fc[u];
        }
        out[blockIdx.x * NBATCH + tix] = s;
    }
}

extern "C" void kernel_launch(void* const* d_in, const int* in_sizes, int n_in,
                              void* d_out, int out_size, void* d_ws, size_t ws_size,
                              hipStream_t stream) {
    const float* x    = (const float*)d_in[0];
    const float* W_ih = (const float*)d_in[1];
    const float* W_hh = (const float*)d_in[2];
    const float* b_ih = (const float*)d_in[3];
    const float* b_hh = (const float*)d_in[4];
    const float* W_fc = (const float*)d_in[5];
    const float* b_fc = (const float*)d_in[6];
    float* out = (float*)d_out;
    const int Bn = in_sizes[0] / (T_LEN * IN_D);   // 8192
    lstm_mfma4<<<dim3(Bn / NBATCH), dim3(NT), 0, stream>>>(
        x, W_ih, W_hh, b_ih, b_hh, W_fc, b_fc, out);
}